// Round 13
// baseline (320.847 us; speedup 1.0000x reference)
//
#include <hip/hip_runtime.h>
#include <hip/hip_bf16.h>
#include <hip/hip_fp16.h>

#define NBKT 512  // allocated buckets (used: (N+255)>>8 = 391)

typedef _Float16 f16x8 __attribute__((ext_vector_type(8)));
typedef float f32x4 __attribute__((ext_vector_type(4)));

// ---------------- bucketed CSR build (LDS atomics only) ----------------

// blocks [0,256): per-block LDS histogram over 512 buckets (bucket = col>>8).
// blocks [256, 256+152): fp16 weight converts (independent, saves a launch).
__global__ __launch_bounds__(256) void k_bktA1(const int* __restrict__ ecol,
                                               int* __restrict__ blkBkt, int E, int chunk,
                                               const float* __restrict__ W1,
                                               const float* __restrict__ W2,
                                               const float* __restrict__ Wout,
                                               __half* __restrict__ Wt1,
                                               __half* __restrict__ Wt2,
                                               __half* __restrict__ WtO) {
  int t = threadIdx.x;
  if (blockIdx.x < 256) {
    __shared__ int h[NBKT];
    h[t] = 0;
    h[t + 256] = 0;
    __syncthreads();
    int s = blockIdx.x * chunk, e = min(s + chunk, E);
    for (int i = s + t; i < e; i += 256) atomicAdd(&h[ecol[i] >> 8], 1);
    __syncthreads();
    blkBkt[blockIdx.x * NBKT + t] = h[t];
    blkBkt[blockIdx.x * NBKT + t + 256] = h[t + 256];
  } else {
    int id = (blockIdx.x - 256) * 256 + t;  // 38912 total
    if (id < 32768) {
      const float* W = (id < 16384) ? W1 : W2;
      __half* Wt = (id < 16384) ? Wt1 : Wt2;
      int i = id & 16383;
      int k = i >> 7, c = i & 127;
      Wt[c * 128 + k] = __float2half(W[i]);
    } else if (id < 38912) {
      int i = id - 32768;  // [48][128]: c = i>>7, k = i&127
      int c = i >> 7, k = i & 127;
      WtO[i] = (c < 40) ? __float2half(Wout[k * 40 + c]) : __half(0.0f);
    }
  }
}

// per-bucket exclusive scan over the 256 block counts (in place) + bucket total
__global__ __launch_bounds__(256) void k_bktA2a(int* __restrict__ blkBkt,
                                                int* __restrict__ bktTotal) {
  __shared__ int buf[2][256];
  int b = blockIdx.x, t = threadIdx.x;
  int x = blkBkt[t * NBKT + b];
  int cur = 0;
  buf[0][t] = x;
  __syncthreads();
  int v = x;
  for (int off = 1; off < 256; off <<= 1) {
    v = buf[cur][t];
    if (t >= off) v += buf[cur][t - off];
    buf[cur ^ 1][t] = v;
    cur ^= 1;
    __syncthreads();
  }
  blkBkt[t * NBKT + b] = v - x;  // exclusive
  if (t == 255) bktTotal[b] = v;
}

// scan bucket totals -> bktBase[0..NBKT]; also offs[N] = E
__global__ __launch_bounds__(512) void k_bktA2b(const int* __restrict__ bktTotal,
                                                int* __restrict__ bktBase,
                                                int* __restrict__ offs, int N, int E) {
  __shared__ int buf[2][512];
  int t = threadIdx.x;
  int x = bktTotal[t];
  int cur = 0;
  buf[0][t] = x;
  __syncthreads();
  int v = x;
  for (int off = 1; off < 512; off <<= 1) {
    v = buf[cur][t];
    if (t >= off) v += buf[cur][t - off];
    buf[cur ^ 1][t] = v;
    cur ^= 1;
    __syncthreads();
  }
  bktBase[t] = v - x;  // exclusive
  if (t == 511) bktBase[512] = v;
  if (t == 0) offs[N] = E;
}

// scatter edges into bucket-sorted ebuf: entry = (c&255)<<17 | src
__global__ __launch_bounds__(256) void k_bktA3(const int* __restrict__ erow,
                                               const int* __restrict__ ecol,
                                               const int* __restrict__ blkBkt,
                                               const int* __restrict__ bktBase,
                                               uint* __restrict__ ebuf, int E, int chunk) {
  __shared__ int cur[NBKT];
  int t = threadIdx.x;
  cur[t] = bktBase[t] + blkBkt[blockIdx.x * NBKT + t];
  cur[t + 256] = bktBase[t + 256] + blkBkt[blockIdx.x * NBKT + t + 256];
  __syncthreads();
  int s = blockIdx.x * chunk, e = min(s + chunk, E);
  for (int i = s + t; i < e; i += 256) {
    int c = ecol[i], r = erow[i];
    int pos = atomicAdd(&cur[c >> 8], 1);  // LDS returning atomic
    ebuf[pos] = ((uint)(c & 255) << 17) | (uint)r;
  }
}

// per bucket: count 256 nodes (LDS), write dinv + offs (coalesced)
__global__ __launch_bounds__(256) void k_bktB1(const uint* __restrict__ ebuf,
                                               const int* __restrict__ bktBase,
                                               float* __restrict__ dinv,
                                               int* __restrict__ offs, int N) {
  __shared__ int cnt[256];
  __shared__ int buf[2][256];
  int b = blockIdx.x, t = threadIdx.x;
  int node0 = b << 8;
  cnt[t] = 0;
  __syncthreads();
  int s = bktBase[b], e = bktBase[b + 1];
  for (int i = s + t; i < e; i += 256) atomicAdd(&cnt[ebuf[i] >> 17], 1);
  __syncthreads();
  int x = cnt[t];
  if (node0 + t < N) dinv[node0 + t] = rsqrtf((float)x + 1.0f);  // +1 self loop
  int cur = 0;
  buf[0][t] = x;
  __syncthreads();
  int v = x;
  for (int off = 1; off < 256; off <<= 1) {
    v = buf[cur][t];
    if (t >= off) v += buf[cur][t - off];
    buf[cur ^ 1][t] = v;
    cur ^= 1;
    __syncthreads();
  }
  if (node0 + t < N) offs[node0 + t] = s + v - x;  // global exclusive
}

// per bucket: rank via LDS cursor, write packed adj {w15<<17 | src}
__global__ __launch_bounds__(256) void k_bktB2(const uint* __restrict__ ebuf,
                                               const int* __restrict__ bktBase,
                                               const int* __restrict__ offs,
                                               const float* __restrict__ dinv,
                                               uint* __restrict__ adj, int N) {
  __shared__ int cur[256];
  int b = blockIdx.x, t = threadIdx.x;
  int node0 = b << 8;
  cur[t] = (node0 + t < N) ? offs[node0 + t] : 0;
  __syncthreads();
  int s = bktBase[b], e = bktBase[b + 1];
  for (int i = s + t; i < e; i += 256) {
    uint ent = ebuf[i];
    int clow = (int)(ent >> 17);
    int r = (int)(ent & 0x1FFFFu);
    int pos = atomicAdd(&cur[clow], 1);  // LDS returning atomic
    float w = dinv[r] * dinv[node0 + clow];  // <= 0.5
    uint q = (uint)fminf(w * 65536.0f + 0.5f, 32767.0f);
    adj[pos] = (q << 17) | (uint)r;
  }
}

// ---------------- MFMA GEMM: C[n,128](fp16) = A[n,128] @ W[128,128] ----------------
// B register-resident per wave (128 VGPRs); waves grid-stride over 16-row tiles
// with 2-stage A prefetch; per-wave LDS repack epilogue (no barriers).

template <int A_F32>
__global__ __launch_bounds__(256) void k_gemm_mfma(const void* __restrict__ Aptr,
                                                   const __half* __restrict__ Wt,
                                                   __half* __restrict__ C, int n) {
  __shared__ __half Cs[4][16][136];
  int t = threadIdx.x;
  int wv = t >> 6, l = t & 63;
  int lr = l & 15, lg = l >> 4;

  f16x8 B[8][4];  // 128 VGPRs
#pragma unroll
  for (int nt = 0; nt < 8; ++nt)
#pragma unroll
    for (int ks = 0; ks < 4; ++ks)
      B[nt][ks] = *reinterpret_cast<const f16x8*>(Wt + (nt * 16 + lr) * 128 + ks * 32 + lg * 8);

  int ntiles = (n + 15) >> 4;
  int wgid = blockIdx.x * 4 + wv;
  int wstride = gridDim.x * 4;

  float4 rf_c[8], rf_n[8];
  f16x8 rh_c[4], rh_n[4];

  auto loadA = [&](int tile, float4* rf, f16x8* rh) {
    int arow = tile * 16 + lr;
    int crow = arow < n ? arow : 0;
    if (A_F32) {
      const float* A = (const float*)Aptr + (size_t)crow * 128 + lg * 8;
#pragma unroll
      for (int ks = 0; ks < 4; ++ks) {
        rf[ks * 2] = *reinterpret_cast<const float4*>(A + ks * 32);
        rf[ks * 2 + 1] = *reinterpret_cast<const float4*>(A + ks * 32 + 4);
      }
    } else {
      const __half* A = (const __half*)Aptr + (size_t)crow * 128 + lg * 8;
#pragma unroll
      for (int ks = 0; ks < 4; ++ks) rh[ks] = *reinterpret_cast<const f16x8*>(A + ks * 32);
    }
  };

  if (wgid < ntiles) loadA(wgid, rf_c, rh_c);

  for (int tile = wgid; tile < ntiles; tile += wstride) {
    int tnext = tile + wstride;
    if (tnext < ntiles) loadA(tnext, rf_n, rh_n);

    f16x8 a[4];
    if (A_F32) {
#pragma unroll
      for (int ks = 0; ks < 4; ++ks) {
        float4 u0 = rf_c[ks * 2], u1 = rf_c[ks * 2 + 1];
        f16x8 av;
        av[0] = (_Float16)u0.x; av[1] = (_Float16)u0.y;
        av[2] = (_Float16)u0.z; av[3] = (_Float16)u0.w;
        av[4] = (_Float16)u1.x; av[5] = (_Float16)u1.y;
        av[6] = (_Float16)u1.z; av[7] = (_Float16)u1.w;
        a[ks] = av;
      }
    } else {
#pragma unroll
      for (int ks = 0; ks < 4; ++ks) a[ks] = rh_c[ks];
    }

    f32x4 acc[8];
#pragma unroll
    for (int nt = 0; nt < 8; ++nt) acc[nt] = (f32x4){0.f, 0.f, 0.f, 0.f};
#pragma unroll
    for (int ks = 0; ks < 4; ++ks)
#pragma unroll
      for (int nt = 0; nt < 8; ++nt)
        acc[nt] = __builtin_amdgcn_mfma_f32_16x16x32_f16(a[ks], B[nt][ks], acc[nt], 0, 0, 0);

#pragma unroll
    for (int nt = 0; nt < 8; ++nt)
#pragma unroll
      for (int r = 0; r < 4; ++r)
        Cs[wv][lg * 4 + r][nt * 16 + lr] = __float2half(acc[nt][r]);
    // no barrier: per-wave LDS region, same-wave ds ops are in-order
#pragma unroll
    for (int j = 0; j < 4; ++j) {
      int row = j * 4 + lg;
      int gr = tile * 16 + row;
      if (gr < n)
        *reinterpret_cast<uint4*>(&C[(size_t)gr * 128 + lr * 8]) =
            *reinterpret_cast<const uint4*>(&Cs[wv][row][lr * 8]);
    }

    if (A_F32) {
#pragma unroll
      for (int j = 0; j < 8; ++j) rf_c[j] = rf_n[j];
    } else {
#pragma unroll
      for (int j = 0; j < 4; ++j) rh_c[j] = rh_n[j];
    }
  }
}

// ---------------- Aggregation (+ optional fused MFMA output projection) -------
// z[i] = relu( dinv_i^2*h[i] + sum_e w_e h[src_e] + b ), one wave/node.
// FUSE_OUT=0: write z fp16 to outz.
// FUSE_OUT=1: z -> per-wave LDS (256B), broadcast-read A-frags (all 16 A-rows
//   equal z => every D-row is the answer; no zero-fill needed), 12 MFMA vs
//   register-resident WtO (48 VGPR), lanes 0..15 store out[i][0..40).

template <int FUSE_OUT>
__global__ __launch_bounds__(256) void k_agg(const __half* __restrict__ h,
                                             const int* __restrict__ offs,
                                             const uint* __restrict__ adj,
                                             const float* __restrict__ dinv,
                                             const float* __restrict__ bias,
                                             __half* __restrict__ outz,
                                             const __half* __restrict__ WtO,
                                             const float* __restrict__ bout,
                                             float* __restrict__ outf, int n) {
  int t = threadIdx.x;
  int wid = (blockIdx.x * blockDim.x + t) >> 6;
  wid = __builtin_amdgcn_readfirstlane(wid);  // wave-uniform by construction
  int lane = t & 63;
  if (wid >= n) return;

  f16x8 Bf[3][4];  // FUSE_OUT: 48 VGPRs, WtO[48][128] fp16
  float bb[3];
  if (FUSE_OUT) {
    int lr = lane & 15, lg = lane >> 4;
#pragma unroll
    for (int nt = 0; nt < 3; ++nt) {
#pragma unroll
      for (int ks = 0; ks < 4; ++ks)
        Bf[nt][ks] =
            *reinterpret_cast<const f16x8*>(WtO + (nt * 16 + lr) * 128 + ks * 32 + lg * 8);
      int c = nt * 16 + lr;
      bb[nt] = (c < 40) ? bout[c] : 0.f;
    }
  }

  const __half2* hv = reinterpret_cast<const __half2*>(h);
  float ddst = dinv[wid];
  float w0 = ddst * ddst;
  float2 acc = __half22float2(hv[(size_t)wid * 64 + lane]);
  acc.x *= w0;
  acc.y *= w0;
  int s = offs[wid], e = offs[wid + 1];
  int cnt = e - s;
  const uint* ap = adj + s;
  const float qs = 1.0f / 65536.0f;

  float wm[8];
  __half2 hg[8];
#pragma unroll
  for (int j = 0; j < 8; ++j) {
    uint a = ap[j];                 // adj padded by 8: over-read safe
    bool v = j < cnt;
    int src = v ? (int)(a & 0x1FFFFu) : wid;
    wm[j] = v ? (float)(a >> 17) * qs : 0.f;
    hg[j] = hv[(size_t)src * 64 + lane];
  }
  for (int k0 = 0; k0 < cnt; k0 += 8) {
    int k1 = k0 + 8;
    bool more = k1 < cnt;  // wave-uniform
    float wn[8];
    __half2 hn[8];
    if (more) {
#pragma unroll
      for (int j = 0; j < 8; ++j) {
        uint a = ap[k1 + j];
        bool v = k1 + j < cnt;
        int src = v ? (int)(a & 0x1FFFFu) : wid;
        wn[j] = v ? (float)(a >> 17) * qs : 0.f;
        hn[j] = hv[(size_t)src * 64 + lane];
      }
    }
#pragma unroll
    for (int j = 0; j < 8; ++j) {
      float2 f = __half22float2(hg[j]);
      acc.x = fmaf(wm[j], f.x, acc.x);
      acc.y = fmaf(wm[j], f.y, acc.y);
    }
    if (more) {
#pragma unroll
      for (int j = 0; j < 8; ++j) {
        wm[j] = wn[j];
        hg[j] = hn[j];
      }
    }
  }

  float2 b = reinterpret_cast<const float2*>(bias)[lane];
  acc.x = fmaxf(acc.x + b.x, 0.f);
  acc.y = fmaxf(acc.y + b.y, 0.f);

  if (!FUSE_OUT) {
    reinterpret_cast<__half2*>(outz + (size_t)wid * 128)[lane] =
        __floats2half2_rn(acc.x, acc.y);
  } else {
    __shared__ __half zs[4][136];  // per-wave 256B z row (+pad)
    int wv = t >> 6;
    *reinterpret_cast<__half2*>(&zs[wv][2 * lane]) = __floats2half2_rn(acc.x, acc.y);
    // same-wave LDS write->read: in-order, compiler inserts lgkmcnt
    int lg = lane >> 4;
    f16x8 a[4];
#pragma unroll
    for (int ks = 0; ks < 4; ++ks)
      a[ks] = *reinterpret_cast<const f16x8*>(&zs[wv][ks * 32 + lg * 8]);  // broadcast
    f32x4 acc3[3];
#pragma unroll
    for (int nt = 0; nt < 3; ++nt) acc3[nt] = (f32x4){0.f, 0.f, 0.f, 0.f};
#pragma unroll
    for (int ks = 0; ks < 4; ++ks)
#pragma unroll
      for (int nt = 0; nt < 3; ++nt)
        acc3[nt] = __builtin_amdgcn_mfma_f32_16x16x32_f16(a[ks], Bf[nt][ks], acc3[nt], 0, 0, 0);
    // all D rows equal; lanes 0..15 hold row 0 in reg 0
    if (lane < 16) {
#pragma unroll
      for (int nt = 0; nt < 3; ++nt) {
        int c = nt * 16 + lane;
        if (c < 40) outf[(size_t)wid * 40 + c] = acc3[nt][0] + bb[nt];
      }
    }
  }
}

// ---------------- launch ----------------

extern "C" void kernel_launch(void* const* d_in, const int* in_sizes, int n_in,
                              void* d_out, int out_size, void* d_ws, size_t ws_size,
                              hipStream_t stream) {
  const float* x = (const float*)d_in[0];
  const int* ei = (const int*)d_in[1];
  const float* W1 = (const float*)d_in[2];
  const float* b1 = (const float*)d_in[3];
  const float* W2 = (const float*)d_in[4];
  const float* b2 = (const float*)d_in[5];
  const float* Wout = (const float*)d_in[6];
  const float* bout = (const float*)d_in[7];
  float* out = (float*)d_out;

  const int N = in_sizes[0] / 128;
  const int E = in_sizes[1] / 2;
  const int* erow = ei;      // edge_index[0] = source j
  const int* ecol = ei + E;  // edge_index[1] = target i

  char* ws = (char*)d_ws;
  size_t off = 0;
  auto alloc = [&](size_t bytes) -> void* {
    void* p = ws + off;
    off = (off + bytes + 255) & ~(size_t)255;
    return p;
  };
  int* blkBkt = (int*)alloc((size_t)256 * NBKT * 4);
  int* bktTotal = (int*)alloc(NBKT * 4);
  int* bktBase = (int*)alloc((NBKT + 1) * 4);
  int* offs = (int*)alloc((size_t)(N + 1) * 4);
  float* dinv = (float*)alloc((size_t)N * 4);
  uint* ebuf = (uint*)alloc((size_t)E * 4);
  uint* adj = (uint*)alloc((size_t)(E + 8) * 4);        // +8 pad: pipeline over-read
  __half* Wt1 = (__half*)alloc(128 * 128 * 2);
  __half* Wt2 = (__half*)alloc(128 * 128 * 2);
  __half* WtO = (__half*)alloc(48 * 128 * 2);
  __half* bufH = (__half*)alloc((size_t)N * 128 * 2);   // gemm output (h)
  __half* bufZ = (__half*)alloc((size_t)N * 128 * 2);   // agg1 output (z1)

  int chunk = (E + 255) / 256;       // edges per A-phase block
  int nbk = (N + 255) >> 8;          // used buckets (391)

  k_bktA1<<<256 + 152, 256, 0, stream>>>(ecol, blkBkt, E, chunk, W1, W2, Wout,
                                         Wt1, Wt2, WtO);
  k_bktA2a<<<NBKT, 256, 0, stream>>>(blkBkt, bktTotal);
  k_bktA2b<<<1, 512, 0, stream>>>(bktTotal, bktBase, offs, N, E);
  k_bktA3<<<256, 256, 0, stream>>>(erow, ecol, blkBkt, bktBase, ebuf, E, chunk);
  k_bktB1<<<nbk, 256, 0, stream>>>(ebuf, bktBase, dinv, offs, N);
  k_bktB2<<<nbk, 256, 0, stream>>>(ebuf, bktBase, offs, dinv, adj, N);

  k_gemm_mfma<1><<<512, 256, 0, stream>>>(x, Wt1, bufH, N);
  k_agg<0><<<(N + 3) / 4, 256, 0, stream>>>(bufH, offs, adj, dinv, b1, bufZ,
                                            nullptr, nullptr, nullptr, N);
  k_gemm_mfma<0><<<512, 256, 0, stream>>>(bufZ, Wt2, bufH, N);
  k_agg<1><<<(N + 3) / 4, 256, 0, stream>>>(bufH, offs, adj, dinv, b2, nullptr,
                                            WtO, bout, out, N);
}

// Round 14
// 217.566 us; speedup vs baseline: 1.4747x; 1.4747x over previous
//
#include <hip/hip_runtime.h>
#include <hip/hip_bf16.h>
#include <hip/hip_fp16.h>

#define NBKT 512  // allocated buckets (used: (N+255)>>8 = 391)

typedef _Float16 f16x8 __attribute__((ext_vector_type(8)));
typedef float f32x4 __attribute__((ext_vector_type(4)));

// ---------------- bucketed CSR build (LDS atomics only) ----------------

// blocks [0,256): per-block LDS histogram over 512 buckets (bucket = col>>8).
// blocks [256, 256+152): fp16 weight converts (independent, saves a launch).
__global__ __launch_bounds__(256) void k_bktA1(const int* __restrict__ ecol,
                                               int* __restrict__ blkBkt, int E, int chunk,
                                               const float* __restrict__ W1,
                                               const float* __restrict__ W2,
                                               const float* __restrict__ Wout,
                                               __half* __restrict__ Wt1,
                                               __half* __restrict__ Wt2,
                                               __half* __restrict__ WtO) {
  int t = threadIdx.x;
  if (blockIdx.x < 256) {
    __shared__ int h[NBKT];
    h[t] = 0;
    h[t + 256] = 0;
    __syncthreads();
    int s = blockIdx.x * chunk, e = min(s + chunk, E);
    for (int i = s + t; i < e; i += 256) atomicAdd(&h[ecol[i] >> 8], 1);
    __syncthreads();
    blkBkt[blockIdx.x * NBKT + t] = h[t];
    blkBkt[blockIdx.x * NBKT + t + 256] = h[t + 256];
  } else {
    int id = (blockIdx.x - 256) * 256 + t;  // 38912 total
    if (id < 32768) {
      const float* W = (id < 16384) ? W1 : W2;
      __half* Wt = (id < 16384) ? Wt1 : Wt2;
      int i = id & 16383;
      int k = i >> 7, c = i & 127;
      Wt[c * 128 + k] = __float2half(W[i]);
    } else if (id < 38912) {
      int i = id - 32768;  // [48][128]: c = i>>7, k = i&127
      int c = i >> 7, k = i & 127;
      WtO[i] = (c < 40) ? __float2half(Wout[k * 40 + c]) : __half(0.0f);
    }
  }
}

// per-bucket exclusive scan over the 256 block counts (in place) + bucket total
__global__ __launch_bounds__(256) void k_bktA2a(int* __restrict__ blkBkt,
                                                int* __restrict__ bktTotal) {
  __shared__ int buf[2][256];
  int b = blockIdx.x, t = threadIdx.x;
  int x = blkBkt[t * NBKT + b];
  int cur = 0;
  buf[0][t] = x;
  __syncthreads();
  int v = x;
  for (int off = 1; off < 256; off <<= 1) {
    v = buf[cur][t];
    if (t >= off) v += buf[cur][t - off];
    buf[cur ^ 1][t] = v;
    cur ^= 1;
    __syncthreads();
  }
  blkBkt[t * NBKT + b] = v - x;  // exclusive
  if (t == 255) bktTotal[b] = v;
}

// scan bucket totals -> bktBase[0..NBKT]; also offs[N] = E
__global__ __launch_bounds__(512) void k_bktA2b(const int* __restrict__ bktTotal,
                                                int* __restrict__ bktBase,
                                                int* __restrict__ offs, int N, int E) {
  __shared__ int buf[2][512];
  int t = threadIdx.x;
  int x = bktTotal[t];
  int cur = 0;
  buf[0][t] = x;
  __syncthreads();
  int v = x;
  for (int off = 1; off < 512; off <<= 1) {
    v = buf[cur][t];
    if (t >= off) v += buf[cur][t - off];
    buf[cur ^ 1][t] = v;
    cur ^= 1;
    __syncthreads();
  }
  bktBase[t] = v - x;  // exclusive
  if (t == 511) bktBase[512] = v;
  if (t == 0) offs[N] = E;
}

// scatter edges into bucket-sorted ebuf: entry = (c&255)<<17 | src
__global__ __launch_bounds__(256) void k_bktA3(const int* __restrict__ erow,
                                               const int* __restrict__ ecol,
                                               const int* __restrict__ blkBkt,
                                               const int* __restrict__ bktBase,
                                               uint* __restrict__ ebuf, int E, int chunk) {
  __shared__ int cur[NBKT];
  int t = threadIdx.x;
  cur[t] = bktBase[t] + blkBkt[blockIdx.x * NBKT + t];
  cur[t + 256] = bktBase[t + 256] + blkBkt[blockIdx.x * NBKT + t + 256];
  __syncthreads();
  int s = blockIdx.x * chunk, e = min(s + chunk, E);
  for (int i = s + t; i < e; i += 256) {
    int c = ecol[i], r = erow[i];
    int pos = atomicAdd(&cur[c >> 8], 1);  // LDS returning atomic
    ebuf[pos] = ((uint)(c & 255) << 17) | (uint)r;
  }
}

// per bucket: count 256 nodes (LDS), write dinv + offs (coalesced)
__global__ __launch_bounds__(256) void k_bktB1(const uint* __restrict__ ebuf,
                                               const int* __restrict__ bktBase,
                                               float* __restrict__ dinv,
                                               int* __restrict__ offs, int N) {
  __shared__ int cnt[256];
  __shared__ int buf[2][256];
  int b = blockIdx.x, t = threadIdx.x;
  int node0 = b << 8;
  cnt[t] = 0;
  __syncthreads();
  int s = bktBase[b], e = bktBase[b + 1];
  for (int i = s + t; i < e; i += 256) atomicAdd(&cnt[ebuf[i] >> 17], 1);
  __syncthreads();
  int x = cnt[t];
  if (node0 + t < N) dinv[node0 + t] = rsqrtf((float)x + 1.0f);  // +1 self loop
  int cur = 0;
  buf[0][t] = x;
  __syncthreads();
  int v = x;
  for (int off = 1; off < 256; off <<= 1) {
    v = buf[cur][t];
    if (t >= off) v += buf[cur][t - off];
    buf[cur ^ 1][t] = v;
    cur ^= 1;
    __syncthreads();
  }
  if (node0 + t < N) offs[node0 + t] = s + v - x;  // global exclusive
}

// per bucket: rank via LDS cursor, write packed adj {w15<<17 | src}
__global__ __launch_bounds__(256) void k_bktB2(const uint* __restrict__ ebuf,
                                               const int* __restrict__ bktBase,
                                               const int* __restrict__ offs,
                                               const float* __restrict__ dinv,
                                               uint* __restrict__ adj, int N) {
  __shared__ int cur[256];
  int b = blockIdx.x, t = threadIdx.x;
  int node0 = b << 8;
  cur[t] = (node0 + t < N) ? offs[node0 + t] : 0;
  __syncthreads();
  int s = bktBase[b], e = bktBase[b + 1];
  for (int i = s + t; i < e; i += 256) {
    uint ent = ebuf[i];
    int clow = (int)(ent >> 17);
    int r = (int)(ent & 0x1FFFFu);
    int pos = atomicAdd(&cur[clow], 1);  // LDS returning atomic
    float w = dinv[r] * dinv[node0 + clow];  // <= 0.5
    uint q = (uint)fminf(w * 65536.0f + 0.5f, 32767.0f);
    adj[pos] = (q << 17) | (uint)r;
  }
}

// ---------------- MFMA GEMM: C[n,128](fp16) = A[n,128] @ W[128,128] ----------------
// B register-resident per wave (128 VGPRs); waves grid-stride over 16-row tiles
// with 2-stage A prefetch; per-wave LDS repack epilogue (no barriers).

template <int A_F32>
__global__ __launch_bounds__(256) void k_gemm_mfma(const void* __restrict__ Aptr,
                                                   const __half* __restrict__ Wt,
                                                   __half* __restrict__ C, int n) {
  __shared__ __half Cs[4][16][136];
  int t = threadIdx.x;
  int wv = t >> 6, l = t & 63;
  int lr = l & 15, lg = l >> 4;

  f16x8 B[8][4];  // 128 VGPRs
#pragma unroll
  for (int nt = 0; nt < 8; ++nt)
#pragma unroll
    for (int ks = 0; ks < 4; ++ks)
      B[nt][ks] = *reinterpret_cast<const f16x8*>(Wt + (nt * 16 + lr) * 128 + ks * 32 + lg * 8);

  int ntiles = (n + 15) >> 4;
  int wgid = blockIdx.x * 4 + wv;
  int wstride = gridDim.x * 4;

  float4 rf_c[8], rf_n[8];
  f16x8 rh_c[4], rh_n[4];

  auto loadA = [&](int tile, float4* rf, f16x8* rh) {
    int arow = tile * 16 + lr;
    int crow = arow < n ? arow : 0;
    if (A_F32) {
      const float* A = (const float*)Aptr + (size_t)crow * 128 + lg * 8;
#pragma unroll
      for (int ks = 0; ks < 4; ++ks) {
        rf[ks * 2] = *reinterpret_cast<const float4*>(A + ks * 32);
        rf[ks * 2 + 1] = *reinterpret_cast<const float4*>(A + ks * 32 + 4);
      }
    } else {
      const __half* A = (const __half*)Aptr + (size_t)crow * 128 + lg * 8;
#pragma unroll
      for (int ks = 0; ks < 4; ++ks) rh[ks] = *reinterpret_cast<const f16x8*>(A + ks * 32);
    }
  };

  if (wgid < ntiles) loadA(wgid, rf_c, rh_c);

  for (int tile = wgid; tile < ntiles; tile += wstride) {
    int tnext = tile + wstride;
    if (tnext < ntiles) loadA(tnext, rf_n, rh_n);

    f16x8 a[4];
    if (A_F32) {
#pragma unroll
      for (int ks = 0; ks < 4; ++ks) {
        float4 u0 = rf_c[ks * 2], u1 = rf_c[ks * 2 + 1];
        f16x8 av;
        av[0] = (_Float16)u0.x; av[1] = (_Float16)u0.y;
        av[2] = (_Float16)u0.z; av[3] = (_Float16)u0.w;
        av[4] = (_Float16)u1.x; av[5] = (_Float16)u1.y;
        av[6] = (_Float16)u1.z; av[7] = (_Float16)u1.w;
        a[ks] = av;
      }
    } else {
#pragma unroll
      for (int ks = 0; ks < 4; ++ks) a[ks] = rh_c[ks];
    }

    f32x4 acc[8];
#pragma unroll
    for (int nt = 0; nt < 8; ++nt) acc[nt] = (f32x4){0.f, 0.f, 0.f, 0.f};
#pragma unroll
    for (int ks = 0; ks < 4; ++ks)
#pragma unroll
      for (int nt = 0; nt < 8; ++nt)
        acc[nt] = __builtin_amdgcn_mfma_f32_16x16x32_f16(a[ks], B[nt][ks], acc[nt], 0, 0, 0);

#pragma unroll
    for (int nt = 0; nt < 8; ++nt)
#pragma unroll
      for (int r = 0; r < 4; ++r)
        Cs[wv][lg * 4 + r][nt * 16 + lr] = __float2half(acc[nt][r]);
    // no barrier: per-wave LDS region, same-wave ds ops are in-order
#pragma unroll
    for (int j = 0; j < 4; ++j) {
      int row = j * 4 + lg;
      int gr = tile * 16 + row;
      if (gr < n)
        *reinterpret_cast<uint4*>(&C[(size_t)gr * 128 + lr * 8]) =
            *reinterpret_cast<const uint4*>(&Cs[wv][row][lr * 8]);
    }

    if (A_F32) {
#pragma unroll
      for (int j = 0; j < 8; ++j) rf_c[j] = rf_n[j];
    } else {
#pragma unroll
      for (int j = 0; j < 4; ++j) rh_c[j] = rh_n[j];
    }
  }
}

// ---------------- Aggregation ----------------
// z[i](fp16) = relu( dinv_i^2*h[i] + sum_e w_e h[src_e] + b ), one wave/node,
// fp16 h gathered as __half2, f32 accumulate. Packed 4B adjacency
// {w15<<17 | src} via wave-uniform scalar loads; 8-deep register pipeline;
// pad slots (own row, w=0).

__global__ __launch_bounds__(256) void k_agg(const __half* __restrict__ h,
                                             const int* __restrict__ offs,
                                             const uint* __restrict__ adj,
                                             const float* __restrict__ dinv,
                                             const float* __restrict__ bias,
                                             __half* __restrict__ out, int n) {
  int wid = (blockIdx.x * blockDim.x + threadIdx.x) >> 6;
  wid = __builtin_amdgcn_readfirstlane(wid);  // wave-uniform by construction
  int lane = threadIdx.x & 63;
  if (wid >= n) return;
  const __half2* hv = reinterpret_cast<const __half2*>(h);
  float ddst = dinv[wid];
  float w0 = ddst * ddst;
  float2 acc = __half22float2(hv[(size_t)wid * 64 + lane]);
  acc.x *= w0;
  acc.y *= w0;
  int s = offs[wid], e = offs[wid + 1];
  int cnt = e - s;
  const uint* ap = adj + s;
  const float qs = 1.0f / 65536.0f;

  float wm[8];
  __half2 hg[8];
#pragma unroll
  for (int j = 0; j < 8; ++j) {
    uint a = ap[j];                 // adj padded by 8: over-read safe
    bool v = j < cnt;
    int src = v ? (int)(a & 0x1FFFFu) : wid;
    wm[j] = v ? (float)(a >> 17) * qs : 0.f;
    hg[j] = hv[(size_t)src * 64 + lane];
  }
  for (int k0 = 0; k0 < cnt; k0 += 8) {
    int k1 = k0 + 8;
    bool more = k1 < cnt;  // wave-uniform
    float wn[8];
    __half2 hn[8];
    if (more) {
#pragma unroll
      for (int j = 0; j < 8; ++j) {
        uint a = ap[k1 + j];
        bool v = k1 + j < cnt;
        int src = v ? (int)(a & 0x1FFFFu) : wid;
        wn[j] = v ? (float)(a >> 17) * qs : 0.f;
        hn[j] = hv[(size_t)src * 64 + lane];
      }
    }
#pragma unroll
    for (int j = 0; j < 8; ++j) {
      float2 f = __half22float2(hg[j]);
      acc.x = fmaf(wm[j], f.x, acc.x);
      acc.y = fmaf(wm[j], f.y, acc.y);
    }
    if (more) {
#pragma unroll
      for (int j = 0; j < 8; ++j) {
        wm[j] = wn[j];
        hg[j] = hn[j];
      }
    }
  }

  float2 b = reinterpret_cast<const float2*>(bias)[lane];
  acc.x = fmaxf(acc.x + b.x, 0.f);
  acc.y = fmaxf(acc.y + b.y, 0.f);
  reinterpret_cast<__half2*>(out + (size_t)wid * 128)[lane] = __floats2half2_rn(acc.x, acc.y);
}

// ---------------- MFMA output GEMM: out[n,40](f32) = Z[n,128](fp16) @ Wout + b ----
// WoT zero-padded to [48][128] fp16; B register-resident (12 frags, 48 VGPRs);
// waves grid-stride over 16-row tiles; bias in-register; per-wave LDS repack
// (no barriers) then coalesced float4 stores of 40-f32 rows.

__global__ __launch_bounds__(256) void k_gemm_out(const __half* __restrict__ Z,
                                                  const __half* __restrict__ WtO,
                                                  const float* __restrict__ bout,
                                                  float* __restrict__ out, int n) {
  __shared__ float Cs[4][16][52];
  int t = threadIdx.x;
  int wv = t >> 6, l = t & 63;
  int lr = l & 15, lg = l >> 4;

  f16x8 B[3][4];  // 48 VGPRs
#pragma unroll
  for (int nt = 0; nt < 3; ++nt)
#pragma unroll
    for (int ks = 0; ks < 4; ++ks)
      B[nt][ks] = *reinterpret_cast<const f16x8*>(WtO + (nt * 16 + lr) * 128 + ks * 32 + lg * 8);

  float bb[3];
#pragma unroll
  for (int nt = 0; nt < 3; ++nt) {
    int c = nt * 16 + lr;
    bb[nt] = (c < 40) ? bout[c] : 0.f;
  }

  int ntiles = (n + 15) >> 4;
  int wgid = blockIdx.x * 4 + wv;
  int wstride = gridDim.x * 4;

  f16x8 rh_c[4], rh_n[4];
  auto loadA = [&](int tile, f16x8* rh) {
    int arow = tile * 16 + lr;
    int crow = arow < n ? arow : 0;
    const __half* A = Z + (size_t)crow * 128 + lg * 8;
#pragma unroll
    for (int ks = 0; ks < 4; ++ks) rh[ks] = *reinterpret_cast<const f16x8*>(A + ks * 32);
  };

  if (wgid < ntiles) loadA(wgid, rh_c);

  for (int tile = wgid; tile < ntiles; tile += wstride) {
    int tnext = tile + wstride;
    if (tnext < ntiles) loadA(tnext, rh_n);

    f32x4 acc[3];
#pragma unroll
    for (int nt = 0; nt < 3; ++nt) acc[nt] = (f32x4){0.f, 0.f, 0.f, 0.f};
#pragma unroll
    for (int ks = 0; ks < 4; ++ks)
#pragma unroll
      for (int nt = 0; nt < 3; ++nt)
        acc[nt] = __builtin_amdgcn_mfma_f32_16x16x32_f16(rh_c[ks], B[nt][ks], acc[nt], 0, 0, 0);

#pragma unroll
    for (int nt = 0; nt < 3; ++nt)
#pragma unroll
      for (int r = 0; r < 4; ++r)
        Cs[wv][lg * 4 + r][nt * 16 + lr] = acc[nt][r] + bb[nt];
    // no barrier: per-wave LDS region, same-wave ds ops are in-order
#pragma unroll
    for (int j = 0; j < 3; ++j) {
      int f = l + j * 64;  // 160 float4 chunks = 16 rows x 10
      if (f < 160) {
        int row = f / 10, c4 = f - row * 10;
        int gr = tile * 16 + row;
        if (gr < n)
          *reinterpret_cast<float4*>(&out[(size_t)gr * 40 + c4 * 4]) =
              *reinterpret_cast<const float4*>(&Cs[wv][row][c4 * 4]);
      }
    }
#pragma unroll
    for (int j = 0; j < 4; ++j) rh_c[j] = rh_n[j];
  }
}

// ---------------- launch ----------------

extern "C" void kernel_launch(void* const* d_in, const int* in_sizes, int n_in,
                              void* d_out, int out_size, void* d_ws, size_t ws_size,
                              hipStream_t stream) {
  const float* x = (const float*)d_in[0];
  const int* ei = (const int*)d_in[1];
  const float* W1 = (const float*)d_in[2];
  const float* b1 = (const float*)d_in[3];
  const float* W2 = (const float*)d_in[4];
  const float* b2 = (const float*)d_in[5];
  const float* Wout = (const float*)d_in[6];
  const float* bout = (const float*)d_in[7];
  float* out = (float*)d_out;

  const int N = in_sizes[0] / 128;
  const int E = in_sizes[1] / 2;
  const int* erow = ei;      // edge_index[0] = source j
  const int* ecol = ei + E;  // edge_index[1] = target i

  char* ws = (char*)d_ws;
  size_t off = 0;
  auto alloc = [&](size_t bytes) -> void* {
    void* p = ws + off;
    off = (off + bytes + 255) & ~(size_t)255;
    return p;
  };
  int* blkBkt = (int*)alloc((size_t)256 * NBKT * 4);
  int* bktTotal = (int*)alloc(NBKT * 4);
  int* bktBase = (int*)alloc((NBKT + 1) * 4);
  int* offs = (int*)alloc((size_t)(N + 1) * 4);
  float* dinv = (float*)alloc((size_t)N * 4);
  uint* ebuf = (uint*)alloc((size_t)E * 4);
  uint* adj = (uint*)alloc((size_t)(E + 8) * 4);        // +8 pad: pipeline over-read
  __half* Wt1 = (__half*)alloc(128 * 128 * 2);
  __half* Wt2 = (__half*)alloc(128 * 128 * 2);
  __half* WtO = (__half*)alloc(48 * 128 * 2);
  __half* bufH = (__half*)alloc((size_t)N * 128 * 2);   // gemm output (h)
  __half* bufZ = (__half*)alloc((size_t)N * 128 * 2);   // agg output (z)

  int chunk = (E + 255) / 256;       // edges per A-phase block
  int nbk = (N + 255) >> 8;          // used buckets (391)

  k_bktA1<<<256 + 152, 256, 0, stream>>>(ecol, blkBkt, E, chunk, W1, W2, Wout,
                                         Wt1, Wt2, WtO);
  k_bktA2a<<<NBKT, 256, 0, stream>>>(blkBkt, bktTotal);
  k_bktA2b<<<1, 512, 0, stream>>>(bktTotal, bktBase, offs, N, E);
  k_bktA3<<<256, 256, 0, stream>>>(erow, ecol, blkBkt, bktBase, ebuf, E, chunk);
  k_bktB1<<<nbk, 256, 0, stream>>>(ebuf, bktBase, dinv, offs, N);
  k_bktB2<<<nbk, 256, 0, stream>>>(ebuf, bktBase, offs, dinv, adj, N);

  k_gemm_mfma<1><<<512, 256, 0, stream>>>(x, Wt1, bufH, N);
  k_agg<<<(N + 3) / 4, 256, 0, stream>>>(bufH, offs, adj, dinv, b1, bufZ, N);
  k_gemm_mfma<0><<<512, 256, 0, stream>>>(bufZ, Wt2, bufH, N);
  k_agg<<<(N + 3) / 4, 256, 0, stream>>>(bufH, offs, adj, dinv, b2, bufZ, N);
  k_gemm_out<<<512, 256, 0, stream>>>(bufZ, WtO, bout, out, N);
}